// Round 3
// baseline (490.878 us; speedup 1.0000x reference)
//
#include <hip/hip_runtime.h>
#include <cstdint>
#include <cstddef>

typedef _Float16 f16;
typedef _Float16 f16x8 __attribute__((ext_vector_type(8)));
typedef float f32x4 __attribute__((ext_vector_type(4)));

#define AS1 __attribute__((address_space(1)))
#define AS3 __attribute__((address_space(3)))

// async 16B global->LDS, per-lane source addr, LDS dst = wave-uniform base + lane*16
__device__ __forceinline__ void gl_lds16(const void* g, void* l) {
  __builtin_amdgcn_global_load_lds((AS1 void*)g, (AS3 void*)l, 16u, 0, 0u);
}

// c_tab[parity][a(tap)][i(conv-weight idx)] — folded FIR/upsample coefficients
__constant__ float c_tab[2][3][3] = {
  {{0.75f, 0.25f, 0.00f}, {0.25f, 0.75f, 0.75f}, {0.00f, 0.00f, 0.25f}},
  {{0.25f, 0.00f, 0.00f}, {0.75f, 0.75f, 0.25f}, {0.00f, 0.25f, 0.75f}}
};

// =====================================================================================
// Fused prep (unchanged from R2):
//  blocks [0,256):        build Et3[c8][ay3][ax3][jj1024][ic32] f16 from W (f32)
//  blocks [256,256+4224): fill Ah[n8][y66][x66][ic256] f16 (NCHW->NHWC + zeroed halo)
// =====================================================================================
__global__ __launch_bounds__(256) void prep_k(const float* __restrict__ W,
                                              const float* __restrict__ In,
                                              f16* __restrict__ Et,
                                              f16* __restrict__ Ah) {
  const int b = blockIdx.x;
  const int tid = threadIdx.x;
  if (b < 256) {
    const int oc = b;
    const int ic = tid;
    const int c = ic >> 5, icl = ic & 31;
    float w[9];
    const float* wp = W + ((size_t)oc * 256 + ic) * 9;
#pragma unroll
    for (int t = 0; t < 9; ++t) w[t] = wp[t];
#pragma unroll
    for (int py = 0; py < 2; ++py)
#pragma unroll
      for (int px = 0; px < 2; ++px) {
        const int jj = oc * 4 + py * 2 + px;
#pragma unroll
        for (int ay = 0; ay < 3; ++ay)
#pragma unroll
          for (int ax = 0; ax < 3; ++ax) {
            float s = 0.f;
#pragma unroll
            for (int iy = 0; iy < 3; ++iy)
#pragma unroll
              for (int ix = 0; ix < 3; ++ix)
                s += w[iy * 3 + ix] * c_tab[py][ay][iy] * c_tab[px][ax][ix];
            Et[((size_t)(((c * 3 + ay) * 3 + ax) * 1024 + jj)) * 32 + icl] = (f16)s;
          }
      }
  } else {
    const int bid2 = b - 256;
    const int icc = bid2 & 7;
    const int v = bid2 >> 3;       // 0..527
    const int n = v / 66;
    const int yp = v - n * 66;     // y' in 0..65
    const int ic0 = icc * 32;
    const int icl = tid & 31, x8 = tid >> 5;
    f16* rowbase = Ah + ((size_t)(n * 66 + yp) * 66) * 256 + ic0;
    if (yp == 0 || yp == 65) {
#pragma unroll
      for (int i = 0; i < 9; ++i) {
        const int xp = i * 8 + x8;
        if (xp < 66) rowbase[(size_t)xp * 256 + icl] = (f16)0.f;
      }
    } else {
      const int y = yp - 1;
      __shared__ float tile[32][65];
      const int xl = tid & 63, icl4 = tid >> 6;
      const float* src = In + (((size_t)(n * 256 + ic0)) * 64 + y) * 64;
#pragma unroll
      for (int i = 0; i < 8; ++i) {
        const int icl_ = i * 4 + icl4;
        tile[icl_][xl] = src[(size_t)icl_ * 4096 + xl];
      }
      __syncthreads();
      f16* dst = rowbase + 256;  // x'=1
#pragma unroll
      for (int i = 0; i < 8; ++i) {
        const int x = i * 8 + x8;
        dst[(size_t)x * 256 + icl] = (f16)tile[icl][x];
      }
      if (x8 == 0) {
        rowbase[icl] = (f16)0.f;
        rowbase[(size_t)65 * 256 + icl] = (f16)0.f;
      }
    }
  }
}

// =====================================================================================
// Restructured K-loop: 8 c-chunks. Per chunk: B = all 9 taps x 128 jj x 32 ic staged
// to LDS (73.7 KB, one barrier pair); A-fragments loaded DIRECT global->VGPR per tap
// (16 B/lane, L1-resident window, compiler fine-grained vmcnt pipelining).
// =====================================================================================
__global__ __launch_bounds__(256, 2) void gemm_k(const f16* __restrict__ Ah,
                                                 const f16* __restrict__ Et,
                                                 const float* __restrict__ bias,
                                                 float* __restrict__ out) {
  __shared__ __align__(16) f16 lB[36864];  // [ayax9][jj128][ic32] = 73728 B
  char* const lBb = (char*)lB;
  const int tid = threadIdx.x;
  const int wave = tid >> 6;
  const int lane = tid & 63;
  const int bid = blockIdx.x;   // 2048; nt-outer: same-mt blocks 256 apart -> same XCD
  const int mt = bid & 255;
  const int nt = bid >> 8;
  const int m0 = mt * 128;
  const int jj0 = nt * 128;
  const int n = m0 >> 12;
  const int y0 = (m0 >> 6) & 63;  // even; tile covers y0,y0+1 (x full 0..63)

  // ---- B staging: 72 slots of 1KB, wave w takes s = w + 4j, j<18 ----
  int goB[18];
#pragma unroll
  for (int j = 0; j < 18; ++j) {
    const int s = wave + 4 * j;
    const int ayax = s >> 3, sub = s & 7;
    goB[j] = ayax * 65536 + (sub * 16 + (lane >> 2)) * 64 + (lane & 3) * 16;
  }

  // ---- A direct-load per-lane offsets ----
  const int wm = wave >> 1, wn = wave & 1;  // 2x2 wave grid, each 64(m) x 64(jj)
  const int lr = lane & 15;
  const int il = lane >> 4;
  int vOffA[4];
#pragma unroll
  for (int mi = 0; mi < 4; ++mi) {
    const int ml = mi * 16 + lr;               // m&63 (x), row = wm
    vOffA[mi] = (wm * 66 + ml) * 512 + il * 16;
  }
  const char* const sA = (const char*)Ah + ((size_t)(n * 66 + y0) * 66) * 512;
  const char* const bE = (const char*)Et + (size_t)jj0 * 64;
  const int rdB = lr * 64 + il * 16;  // + ayax*8192 + wn*4096 + ni*1024

  const f32x4 vzero = {0.f, 0.f, 0.f, 0.f};
  f32x4 acc[4][4];
#pragma unroll
  for (int i = 0; i < 4; ++i)
#pragma unroll
    for (int j = 0; j < 4; ++j) acc[i][j] = vzero;

#pragma unroll 1
  for (int c = 0; c < 8; ++c) {
    const char* bP = bE + (size_t)c * 589824;  // 9*65536 per c
    __syncthreads();  // previous chunk's B reads done
#pragma unroll
    for (int j = 0; j < 18; ++j) gl_lds16(bP + goB[j], lBb + (wave + 4 * j) * 1024);
    __syncthreads();  // drain staging

    const char* aC = sA + c * 64;  // ic chunk
#pragma unroll
    for (int ay = 0; ay < 3; ++ay) {
#pragma unroll
      for (int ax = 0; ax < 3; ++ax) {
        const int ayax = ay * 3 + ax;
        const char* aT = aC + (ay * 66 + ax) * 512;
        f16x8 af[4], bf[4];
#pragma unroll
        for (int mi = 0; mi < 4; ++mi)
          af[mi] = *(const f16x8*)(aT + vOffA[mi]);  // global, 16B/lane
#pragma unroll
        for (int ni = 0; ni < 4; ++ni)
          bf[ni] = *(const f16x8*)(lBb + rdB + ayax * 8192 + wn * 4096 + ni * 1024);
#pragma unroll
        for (int mi = 0; mi < 4; ++mi)
#pragma unroll
          for (int ni = 0; ni < 4; ++ni)
            acc[mi][ni] =
                __builtin_amdgcn_mfma_f32_16x16x32_f16(af[mi], bf[ni], acc[mi][ni], 0, 0, 0);
      }
    }
  }

  // ---- epilogue: C layout col=lane&15 (jj), row=(lane>>4)*4+v (m) — verified R1/R2 ----
  const int yw = y0 + wm;
#pragma unroll
  for (int ni = 0; ni < 4; ++ni) {
    const int jj = jj0 + wn * 64 + ni * 16 + lr;
    const int oc = jj >> 2;
    const int py = (jj >> 1) & 1, px = jj & 1;
    const float bv = bias[oc];
    const int oy = 2 * yw + py;
    float* orow = out + ((size_t)(n * 256 + oc) * 128 + oy) * 128;
#pragma unroll
    for (int mi = 0; mi < 4; ++mi) {
      const int xb = mi * 16 + il * 4;
#pragma unroll
      for (int v = 0; v < 4; ++v) {
        orow[2 * (xb + v) + px] = acc[mi][ni][v] + bv;
      }
    }
  }
}

// ---------------- fallback (ws too small): direct, slow, correct ---------------------
__global__ __launch_bounds__(256) void fallback_k(const float* __restrict__ In,
                                                  const float* __restrict__ W,
                                                  const float* __restrict__ bias,
                                                  float* __restrict__ out) {
  const size_t idx = (size_t)blockIdx.x * 256 + threadIdx.x;
  const int ox = (int)(idx & 127), oy = (int)((idx >> 7) & 127);
  const int oc = (int)((idx >> 14) & 255);
  const int n = (int)(idx >> 22);
  const int px = ox & 1, py = oy & 1;
  const int x = ox >> 1, y = oy >> 1;
  float cy[3][3], cx[3][3];
#pragma unroll
  for (int a = 0; a < 3; ++a)
#pragma unroll
    for (int i = 0; i < 3; ++i) {
      cy[a][i] = c_tab[py][a][i];
      cx[a][i] = c_tab[px][a][i];
    }
  float acc = 0.f;
  const float* wbase = W + (size_t)oc * 2304;
  for (int ic = 0; ic < 256; ++ic) {
    const float* ib = In + (((size_t)(n * 256 + ic)) * 64 + y) * 64 + x;
    float pin[3][3];
#pragma unroll
    for (int ay = 0; ay < 3; ++ay) {
      const int yy = y + ay - 1;
#pragma unroll
      for (int ax = 0; ax < 3; ++ax) {
        const int xx = x + ax - 1;
        pin[ay][ax] = (yy >= 0 && yy < 64 && xx >= 0 && xx < 64)
                          ? ib[(ay - 1) * 64 + (ax - 1)] : 0.f;
      }
    }
    const float* w = wbase + ic * 9;
    float U[3][3];
#pragma unroll
    for (int ay = 0; ay < 3; ++ay)
#pragma unroll
      for (int ix = 0; ix < 3; ++ix)
        U[ay][ix] = cx[0][ix] * pin[ay][0] + cx[1][ix] * pin[ay][1] + cx[2][ix] * pin[ay][2];
#pragma unroll
    for (int iy = 0; iy < 3; ++iy)
#pragma unroll
      for (int ix = 0; ix < 3; ++ix) {
        const float V = cy[0][iy] * U[0][ix] + cy[1][iy] * U[1][ix] + cy[2][iy] * U[2][ix];
        acc += w[iy * 3 + ix] * V;
      }
  }
  out[idx] = acc + bias[oc];
}

extern "C" void kernel_launch(void* const* d_in, const int* in_sizes, int n_in,
                              void* d_out, int out_size, void* d_ws, size_t ws_size,
                              hipStream_t stream) {
  const float* In = (const float*)d_in[0];    // [8][256][64][64]
  const float* W = (const float*)d_in[1];     // [256][256][3][3]
  const float* bias = (const float*)d_in[2];  // [256]
  float* out = (float*)d_out;                 // [8][256][128][128]

  const size_t E_BYTES = (size_t)1024 * 2304 * 2;       // 4,718,592
  const size_t A_BYTES = (size_t)8 * 66 * 66 * 256 * 2; // 17,842,176

  if (ws_size >= E_BYTES + A_BYTES) {
    f16* Et = (f16*)d_ws;
    f16* Ah = (f16*)((char*)d_ws + E_BYTES);
    prep_k<<<256 + 4224, 256, 0, stream>>>(W, In, Et, Ah);
    gemm_k<<<2048, 256, 0, stream>>>(Ah, Et, bias, out);
  } else {
    fallback_k<<<131072, 256, 0, stream>>>(In, W, bias, out);
  }
}